// Round 18
// baseline (339.076 us; speedup 1.0000x reference)
//
#include <hip/hip_runtime.h>

#define N_PIX 16384
#define CC 192
#define C3 576
#define KTOT 192
#define NCH 32
#define CHUNK 512
#define WTILE 12800   // 64 rows x 200 cols (bf16) = 25600 B per W tile

typedef __bf16 bf16_t;
typedef bf16_t bf16x4 __attribute__((ext_vector_type(4)));
typedef bf16_t bf16x8 __attribute__((ext_vector_type(8)));
typedef float f32x4 __attribute__((ext_vector_type(4)));

struct WPtrs { const float* p[4]; };
struct GArgs { long xoff[16]; long yoff[16]; long woff[16]; int sel[16]; };

// ------- m-outer MFMA GEMM, W via global_load_lds DMA ------------------------
// Per block: X(128n x 192k) B-frags in registers (loaded once, r17-validated);
// W tiles stream L2->LDS via global_load_lds (16B, double-buffered, pre-padded
// bf16 source so the linear DMA lands in the exact [64][200] LDS layout).
// MFMA operands SWAPPED vs r17: D row = n-local(4gi+r), col = m-local(li)
// [m89 C/D map], so each lane stores 4 consecutive n = vector stores.
// Shared k-bijection phi'(gi,e)=8gi+e on both frags (permutation-invariant).
template <typename XT, typename YT, int NC, int NMT>
__global__ __launch_bounds__(256) void gemm_mloop(GArgs ga,
    const XT* __restrict__ X0, const XT* __restrict__ X1,
    YT* __restrict__ Y, const bf16_t* __restrict__ Wpad)
{
    __shared__ __align__(16) bf16_t Wl[2][WTILE];   // 2 x 25.6KB
    const int z = blockIdx.y;
    const XT* __restrict__ Xb = (ga.sel[z] ? X1 : X0) + ga.xoff[z];
    const int n0 = blockIdx.x * 128;
    const int tid = threadIdx.x;
    const int w = tid >> 6;
    const int gi = (tid >> 4) & 3;
    const int li = tid & 15;

    // ---- B-fragments (used as MFMA A-operand) for the whole block, once.
    // elem e -> k = 32t + 8gi + e; lane index li -> n = n0+32w+16ni+li
    bf16x8 xfrag[6][2];
    #pragma unroll
    for (int t = 0; t < 6; ++t)
        #pragma unroll
        for (int ni = 0; ni < 2; ++ni) {
            const XT* xp = Xb + (long)(32 * t + 8 * gi) * N_PIX
                              + n0 + 32 * w + 16 * ni + li;
            bf16x8 v;
            #pragma unroll
            for (int e = 0; e < 8; ++e) v[e] = (bf16_t)xp[(long)e * N_PIX];
            xfrag[t][ni] = v;
        }

    // ---- W tile DMA: 25600B = 6 x 4KB rounds + 1KB tail (wave 0)
    auto dmaW = [&](int it, int buf) {
        const int c = it / NMT, j = it % NMT;
        const char* src = (const char*)(Wpad + ga.woff[z * NC + c]
                                        + (long)j * WTILE);
        char* dst = (char*)&Wl[buf][0];
        #pragma unroll
        for (int r = 0; r < 6; ++r)
            __builtin_amdgcn_global_load_lds(
                (const __attribute__((address_space(1))) void*)
                    (src + r * 4096 + tid * 16),
                (__attribute__((address_space(3))) void*)
                    (dst + r * 4096 + w * 1024),
                16, 0, 0);
        if (w == 0)
            __builtin_amdgcn_global_load_lds(
                (const __attribute__((address_space(1))) void*)
                    (src + 24576 + tid * 16),
                (__attribute__((address_space(3))) void*)(dst + 24576),
                16, 0, 0);
    };

    dmaW(0, 0);
    __syncthreads();                    // drains DMA: Wl[0] ready

    for (int it = 0; it < NC * NMT; ++it) {
        const int cur = it & 1;
        if (it + 1 < NC * NMT) dmaW(it + 1, cur ^ 1);   // async under MFMAs
        f32x4 acc[4][2];
        #pragma unroll
        for (int i = 0; i < 4; ++i)
            #pragma unroll
            for (int jj = 0; jj < 2; ++jj) acc[i][jj] = 0.f;
        #pragma unroll
        for (int t = 0; t < 6; ++t) {
            bf16x8 af[4];
            #pragma unroll
            for (int mi = 0; mi < 4; ++mi)
                af[mi] = *(const bf16x8*)
                    &Wl[cur][(16 * mi + li) * 200 + 32 * t + 8 * gi];
            #pragma unroll
            for (int mi = 0; mi < 4; ++mi)
                #pragma unroll
                for (int ni = 0; ni < 2; ++ni)
                    acc[mi][ni] = __builtin_amdgcn_mfma_f32_16x16x32_bf16(
                        xfrag[t][ni], af[mi], acc[mi][ni], 0, 0, 0);
        }
        // epilogue: lane holds n = ...+4gi+{0..3} (consecutive), m = 16mi+li
        {
            const int c = it / NMT, j = it % NMT;
            YT* Yb = Y + ga.yoff[z * NC + c] + (long)(64 * j) * N_PIX;
            #pragma unroll
            for (int mi = 0; mi < 4; ++mi)
                #pragma unroll
                for (int ni = 0; ni < 2; ++ni) {
                    YT* yp = Yb + (long)(16 * mi + li) * N_PIX
                               + n0 + 32 * w + 16 * ni + 4 * gi;
                    if constexpr (sizeof(YT) == 4) {
                        *(f32x4*)yp = acc[mi][ni];
                    } else {
                        bf16x4 v = { (bf16_t)acc[mi][ni][0],
                                     (bf16_t)acc[mi][ni][1],
                                     (bf16_t)acc[mi][ni][2],
                                     (bf16_t)acc[mi][ni][3] };
                        *(bf16x4*)yp = v;
                    }
                }
        }
        __syncthreads();   // all reads of Wl[cur] done; DMA(it+1) drained
    }
}

// ---------------- weight prep: f32 [576][192] -> padded bf16 tiles ----------
__global__ __launch_bounds__(256) void prep_w(const float* __restrict__ wq,
                                              bf16_t* __restrict__ wpad)
{
    const int j = blockIdx.x, tid = threadIdx.x;
    for (int idx = tid; idx < 64 * 192; idx += 256) {
        const int r = idx / 192, c = idx - r * 192;
        wpad[(long)j * WTILE + r * 200 + c] =
            (bf16_t)wq[(long)(64 * j + r) * KTOT + c];
    }
}

// ---------------- depthwise 3x3 + fused row L2-norm ----------------
__global__ __launch_bounds__(256) void dwconv3b(const bf16_t* __restrict__ Yin,
    const float* __restrict__ wdw, bf16_t* __restrict__ Z,
    float* __restrict__ invn)
{
    const int ch = blockIdx.x, sb = blockIdx.y;
    const int tid = threadIdx.x;
    const int x0 = (tid & 15) << 3;
    const int y0 = (tid >> 4) << 3;
    const bf16_t* __restrict__ inp = Yin + (long)(sb * C3 + ch) * N_PIX;
    bf16_t* __restrict__ outp = Z + (long)(sb * C3 + ch) * N_PIX;
    const float* wch = wdw + ch * 9;
    const float w00 = wch[0], w01 = wch[1], w02 = wch[2];
    const float w10 = wch[3], w11 = wch[4], w12 = wch[5];
    const float w20 = wch[6], w21 = wch[7], w22 = wch[8];
    const bool hasL = (x0 > 0), hasR = (x0 < 120);
    float A[10], B[10], Cr[10];
    auto loadrow = [&](int yy, float* r) {
        if (yy < 0 || yy > 127) {
            #pragma unroll
            for (int i = 0; i < 10; ++i) r[i] = 0.f;
            return;
        }
        const bf16_t* p = inp + (yy << 7);
        bf16x8 v = *(const bf16x8*)(p + x0);
        #pragma unroll
        for (int j = 0; j < 8; ++j) r[1 + j] = (float)v[j];
        r[0] = hasL ? (float)p[x0 - 1] : 0.f;
        r[9] = hasR ? (float)p[x0 + 8] : 0.f;
    };
    loadrow(y0 - 1, A);
    loadrow(y0,     B);
    float ss = 0.f;
    #pragma unroll
    for (int r = 0; r < 8; ++r) {
        loadrow(y0 + r + 1, Cr);
        bf16x8 ov;
        #pragma unroll
        for (int i = 0; i < 8; ++i) {
            float s;
            s = fmaf(w00, A[i],  fmaf(w01, A[i + 1],  w02 * A[i + 2]));
            s = fmaf(w10, B[i],  fmaf(w11, B[i + 1],  fmaf(w12, B[i + 2], s)));
            s = fmaf(w20, Cr[i], fmaf(w21, Cr[i + 1], fmaf(w22, Cr[i + 2], s)));
            ov[i] = (bf16_t)s;
            const float vb = (float)ov[i];
            ss = fmaf(vb, vb, ss);
        }
        *(bf16x8*)(outp + ((y0 + r) << 7) + x0) = ov;
        #pragma unroll
        for (int i = 0; i < 10; ++i) { A[i] = B[i]; B[i] = Cr[i]; }
    }
    if (ch < 384) {
        #pragma unroll
        for (int off = 32; off > 0; off >>= 1) ss += __shfl_down(ss, off);
        __shared__ float red[4];
        if ((tid & 63) == 0) red[tid >> 6] = ss;
        __syncthreads();
        if (tid == 0) {
            const float t = red[0] + red[1] + red[2] + red[3];
            const int row = (sb >> 2) * 1536 + (sb & 3) * 384 + ch;
            invn[row] = 1.f / fmaxf(sqrtf(t), 1e-12f);
        }
    }
}

// ---------------- MFMA score partials: all 4 combos share one LDS stage ------
__global__ __launch_bounds__(256) void scores_mfma(const bf16_t* __restrict__ Z,
                                                   float* __restrict__ part)
{
    const int c = blockIdx.x;
    const int bh = blockIdx.y;
    const int b = bh >> 2, h = bh & 3;
    __shared__ __align__(16) bf16_t T[4][48][72];   // qe, qd, ke, kd
    const int tid = threadIdx.x;
    const int m = tid >> 6;
    const int gi = (tid >> 4) & 3, li = tid & 15;
    const int qs = (m == 1 || m == 3) ? 1 : 0;
    const int ks = (m == 1 || m == 2) ? 1 : 0;
    f32x4 acc[3][3];
    #pragma unroll
    for (int i = 0; i < 3; ++i)
        #pragma unroll
        for (int j = 0; j < 3; ++j) acc[i][j] = 0.f;

    const int nbase = c * CHUNK;
    for (int k0 = 0; k0 < CHUNK; k0 += 64) {
        __syncthreads();
        for (int l = tid; l < 1536; l += 256) {
            const int t = l / 384;
            const int rem = l - t * 384;
            const int r = rem >> 3, s = rem & 7;
            const int sidx = (t < 2) ? t : (t - 2);
            const int qk = (t < 2) ? 0 : 1;
            const bf16_t* gp = Z + ((long)((sidx * 4 + b) * C3 + qk * 192 + h * 48 + r)) * N_PIX
                                 + nbase + k0 + s * 8;
            *(bf16x8*)&T[t][r][s * 8] = *(const bf16x8*)gp;
        }
        __syncthreads();
        #pragma unroll
        for (int k2 = 0; k2 < 64; k2 += 32) {
            bf16x8 af[3], bfr[3];
            #pragma unroll
            for (int i = 0; i < 3; ++i) {
                bf16x4 lo = *(const bf16x4*)&T[qs][16 * i + li][k2 + 4 * gi];
                bf16x4 hi = *(const bf16x4*)&T[qs][16 * i + li][k2 + 16 + 4 * gi];
                af[i] = __builtin_shufflevector(lo, hi, 0, 1, 2, 3, 4, 5, 6, 7);
            }
            #pragma unroll
            for (int j = 0; j < 3; ++j) {
                bf16x4 lo = *(const bf16x4*)&T[2 + ks][16 * j + li][k2 + 4 * gi];
                bf16x4 hi = *(const bf16x4*)&T[2 + ks][16 * j + li][k2 + 16 + 4 * gi];
                bfr[j] = __builtin_shufflevector(lo, hi, 0, 1, 2, 3, 4, 5, 6, 7);
            }
            #pragma unroll
            for (int i = 0; i < 3; ++i)
                #pragma unroll
                for (int j = 0; j < 3; ++j)
                    acc[i][j] = __builtin_amdgcn_mfma_f32_16x16x32_bf16(
                        af[i], bfr[j], acc[i][j], 0, 0, 0);
        }
    }
    const long base = ((long)(m * 16 + bh) * NCH + c) * 2304;
    #pragma unroll
    for (int i = 0; i < 3; ++i)
        #pragma unroll
        for (int j = 0; j < 3; ++j) {
            const int e = 16 * j + li;
            #pragma unroll
            for (int r = 0; r < 4; ++r) {
                const int d = 16 * i + 4 * gi + r;
                part[base + d * 48 + e] = acc[i][j][r];
            }
        }
}

// ---------------- reduce partials, scale by norms+temperature, softmax -------
__global__ __launch_bounds__(256) void reduce_softmax(const float* __restrict__ part,
    const float* __restrict__ invn, const float* __restrict__ temp,
    float* __restrict__ attn)
{
    const int mbh = blockIdx.x;                 // 64
    const int m = mbh >> 4, b = (mbh >> 2) & 3, h = mbh & 3;
    const int qs = (m == 1 || m == 3) ? 1 : 0;
    const int ks = (m == 1 || m == 2) ? 1 : 0;
    __shared__ float sm[48][48];
    const int tid = threadIdx.x;
    const long pbase = (long)mbh * NCH * 2304;
    const float T = temp[h];
    for (int idx = tid; idx < 2304; idx += 256) {
        float v = 0.f;
        #pragma unroll 8
        for (int c = 0; c < NCH; ++c) v += part[pbase + c * 2304 + idx];
        const int d = idx / 48, e = idx % 48;
        const float iq = invn[(qs * 4 + b) * 384 + h * 48 + d];
        const float ik = invn[(ks * 4 + b) * 384 + 192 + h * 48 + e];
        sm[d][e] = v * iq * ik * T;
    }
    __syncthreads();
    if (tid < 48) {
        float mx = -1e30f;
        #pragma unroll
        for (int e = 0; e < 48; ++e) mx = fmaxf(mx, sm[tid][e]);
        float sum = 0.f;
        #pragma unroll
        for (int e = 0; e < 48; ++e) {
            const float v = __expf(sm[tid][e] - mx);
            sm[tid][e] = v;
            sum += v;
        }
        const float inv = 1.f / sum;
        const long abase = (long)mbh * 2304 + (long)tid * 48;
        #pragma unroll
        for (int e = 0; e < 48; ++e) attn[abase + e] = sm[tid][e] * inv;
    }
}

// -------- fold attn into projection; emit padded bf16 W tiles directly ------
// m==3 (inter_de): einsum '...de,bhen->bhdn' SUMS the ellipsis dims.
__global__ __launch_bounds__(256) void make_M(const float* __restrict__ attn,
                                              WPtrs wp, bf16_t* __restrict__ Mpad)
{
    const int h = blockIdx.x & 3;
    const int b = (blockIdx.x >> 2) & 3;
    const int m = blockIdx.x >> 4;              // grid 64
    __shared__ float A[48][48];
    const int tid = threadIdx.x;
    if (m == 3) {
        for (int l = tid; l < 2304; l += 256) {
            float s = 0.f;
            #pragma unroll
            for (int bb = 0; bb < 16; ++bb)
                s += attn[(long)(48 + bb) * 2304 + l];
            A[l / 48][l % 48] = s;
        }
    } else {
        const long ab = (long)(m * 16 + b * 4 + h) * 2304;
        for (int l = tid; l < 2304; l += 256)
            A[l / 48][l % 48] = attn[ab + l];
    }
    __syncthreads();
    const float* W = wp.p[m];
    bf16_t* Mo = Mpad + (long)(m * 4 + b) * 3 * WTILE;
    for (int o = tid >> 4; o < 192; o += 16) {
        const float* wrow = W + (long)o * 192 + h * 48;
        bf16_t* orow = Mo + (long)(o >> 6) * WTILE + (o & 63) * 200 + h * 48;
        for (int e2 = tid & 15; e2 < 48; e2 += 16) {
            float s = 0.f;
            #pragma unroll
            for (int d = 0; d < 48; ++d) s = fmaf(wrow[d], A[d][e2], s);
            orow[e2] = (bf16_t)s;
        }
    }
}

extern "C" void kernel_launch(void* const* d_in, const int* in_sizes, int n_in,
                              void* d_out, int out_size, void* d_ws, size_t ws_size,
                              hipStream_t stream)
{
    const float* e     = (const float*)d_in[0];
    const float* d     = (const float*)d_in[1];
    const float* temp  = (const float*)d_in[2];
    const float* w_qkv = (const float*)d_in[3];
    const float* w_dw  = (const float*)d_in[4];
    const float* w_p1  = (const float*)d_in[5];
    const float* w_p2  = (const float*)d_in[6];
    const float* w_p3  = (const float*)d_in[7];
    const float* w_p4  = (const float*)d_in[8];
    float* out = (float*)d_out;
    float* ws  = (float*)d_ws;

    // workspace layout (float units)
    bf16_t* zraw = (bf16_t*)ws;                // 75,497,472 bf16 (qkv raw)
    bf16_t* zb   = (bf16_t*)(ws + 37748736L);  // 75,497,472 bf16
    float* attn  = ws + 75497472L;             // 147,456
    float* invn  = ws + 75644928L;             // 3,072
    bf16_t* Wqpad = (bf16_t*)(ws + 75648000L); // 9*12800 bf16 = 57,600 f32
    bf16_t* Mpad  = (bf16_t*)(ws + 75710000L); // 16*3*12800 bf16 = 307,200 f32
    // part reuses the zraw region once it's dead (after dwconv3b)
    float* part  = ws;                         // 4,718,592 f32

    const long sXin = (long)CC * N_PIX;
    const long sQKV = (long)C3 * N_PIX;

    // 0) pre-convert qkv weights to padded bf16 tiles
    prep_w<<<dim3(9), 256, 0, stream>>>(w_qkv, Wqpad);
    // 1) pointwise qkv GEMM, bf16 out — z = (s,b) panel; 9 m-tiles per block
    GArgs gq{};
    for (int z = 0; z < 8; ++z) {
        gq.xoff[z] = (long)(z & 3) * sXin;
        gq.yoff[z] = (long)z * sQKV;
        gq.woff[z] = 0;
        gq.sel[z] = z >> 2;
    }
    gemm_mloop<float, bf16_t, 1, 9><<<dim3(128, 8), 256, 0, stream>>>(
        gq, e, d, zraw, Wqpad);
    // 2) depthwise 3x3 (bf16 -> bf16) + fused q/k row norms
    dwconv3b<<<dim3(C3, 8), 256, 0, stream>>>(zraw, w_dw, zb, invn);
    // 3) MFMA score partials, 4 combos fused
    scores_mfma<<<dim3(NCH, 16), 256, 0, stream>>>(zb, part);
    // 4) reduce + scale + softmax
    reduce_softmax<<<dim3(64), 256, 0, stream>>>(part, invn, temp, attn);
    // 5) fold attn into projection matrices (padded bf16 tiles)
    WPtrs wpj; wpj.p[0] = w_p1; wpj.p[1] = w_p2; wpj.p[2] = w_p3; wpj.p[3] = w_p4;
    make_M<<<dim3(64), 256, 0, stream>>>(attn, wpj, Mpad);
    // 6) fused (proj ∘ attn) @ V: z = V panel (s,b); 2 combos x 3 m-tiles per
    //    block, V read ONCE. s=0 panels serve m in {0,3}; s=1 serve {1,2}.
    GArgs gm{};
    for (int z = 0; z < 8; ++z) {
        const int s = z >> 2, b = z & 3;
        gm.xoff[z] = ((long)((s * 4 + b) * C3 + 384)) * N_PIX;
        gm.sel[z] = 0;
        for (int c = 0; c < 2; ++c) {
            const int midx = (s == 0) ? (c ? 3 : 0) : (c ? 2 : 1);
            gm.woff[2 * z + c] = (long)(midx * 4 + b) * 3 * WTILE;
            gm.yoff[2 * z + c] = (long)(midx * 4 + b) * sXin;
        }
    }
    gemm_mloop<bf16_t, float, 2, 3><<<dim3(128, 8), 256, 0, stream>>>(
        gm, zb, zb, out, Mpad);
}

// Round 19
// 304.232 us; speedup vs baseline: 1.1145x; 1.1145x over previous
//
#include <hip/hip_runtime.h>

#define N_PIX 16384
#define CC 192
#define C3 576
#define KTOT 192
#define NCH 32
#define CHUNK 512
#define WTILE 12800   // 64 rows x 200 cols (bf16) = 25600 B per W tile

typedef __bf16 bf16_t;
typedef bf16_t bf16x4 __attribute__((ext_vector_type(4)));
typedef bf16_t bf16x8 __attribute__((ext_vector_type(8)));
typedef float f32x4 __attribute__((ext_vector_type(4)));

struct WPtrs { const float* p[4]; };
struct GArgs { long xoff[16]; long yoff[16]; long woff[16]; int sel[16]; };

// ------- m-outer MFMA GEMM, HBM-line-efficient on all three streams ---------
// r7-r18 invariant decoded: at 205MB/117us the qkv GEMM ran 6.8 B/cyc/CU —
// the per-CU HBM share — but with ~2x line inflation: k-strided X reads
// (4 segments/instr) and bf16 half-line stores (32B per m-row). This round
// fixes transaction SHAPES: (1) Phase A stages X via full-line vector loads
// + one LDS transpose per block into k-major xfrag regs; (2) qkv epilogue
// assembles the 64x128 bf16 tile in LDS and stores 4x256B-contiguous per
// wave instr. W streams via global_load_lds from pre-padded bf16 tiles (r18).
// MFMA operands swapped (D row=n-local, col=m-local [m89]); shared k-bijection
// phi'(gi,e)=8gi+e on both frags (permutation-invariant).
template <typename XT, typename YT, int NC, int NMT>
__global__ __launch_bounds__(256) void gemm_mloop(GArgs ga,
    const XT* __restrict__ X0, const XT* __restrict__ X1,
    YT* __restrict__ Y, const bf16_t* __restrict__ Wpad)
{
    __shared__ __align__(16) bf16_t Wl[2][WTILE];   // 2 x 25.6KB
    __shared__ __align__(16) char Ustage[17408];    // X stage [32][136]XT /
                                                    // epi tile [64][136]bf16
    const int z = blockIdx.y;
    const XT* __restrict__ Xb = (ga.sel[z] ? X1 : X0) + ga.xoff[z];
    const int n0 = blockIdx.x * 128;
    const int tid = threadIdx.x;
    const int w = tid >> 6;
    const int gi = (tid >> 4) & 3;
    const int li = tid & 15;

    // ---- Phase A: full-line X loads -> LDS -> k-major xfrag (once per block)
    bf16x8 xfrag[6][2];
    {
        XT* stg = (XT*)Ustage;              // [32][136]
        const int kr = tid >> 3;            // 0..31
        const int nq = tid & 7;             // 0..7 (16-elem column groups)
        for (int kc = 0; kc < 6; ++kc) {
            const XT* xp = Xb + (long)(32 * kc + kr) * N_PIX + n0 + 16 * nq;
            XT* sp = stg + kr * 136 + 16 * nq;
            if constexpr (sizeof(XT) == 4) {
                f32x4 a = *(const f32x4*)(xp);
                f32x4 b = *(const f32x4*)(xp + 4);
                f32x4 c = *(const f32x4*)(xp + 8);
                f32x4 d4 = *(const f32x4*)(xp + 12);
                *(f32x4*)(sp) = a;   *(f32x4*)(sp + 4) = b;
                *(f32x4*)(sp + 8) = c; *(f32x4*)(sp + 12) = d4;
            } else {
                bf16x8 a = *(const bf16x8*)(xp);
                bf16x8 b = *(const bf16x8*)(xp + 8);
                *(bf16x8*)(sp) = a;  *(bf16x8*)(sp + 8) = b;
            }
            __syncthreads();
            #pragma unroll
            for (int ni = 0; ni < 2; ++ni) {
                const int nn = 32 * w + 16 * ni + li;
                bf16x8 v;
                #pragma unroll
                for (int e = 0; e < 8; ++e)
                    v[e] = (bf16_t)stg[(8 * gi + e) * 136 + nn];
                xfrag[kc][ni] = v;
            }
            __syncthreads();
        }
    }

    // ---- W tile DMA: 25600B = 6 x 4KB rounds + 1KB tail (wave 0)
    auto dmaW = [&](int it, int buf) {
        const int c = it / NMT, j = it % NMT;
        const char* src = (const char*)(Wpad + ga.woff[z * NC + c]
                                        + (long)j * WTILE);
        char* dst = (char*)&Wl[buf][0];
        #pragma unroll
        for (int r = 0; r < 6; ++r)
            __builtin_amdgcn_global_load_lds(
                (const __attribute__((address_space(1))) void*)
                    (src + r * 4096 + tid * 16),
                (__attribute__((address_space(3))) void*)
                    (dst + r * 4096 + w * 1024),
                16, 0, 0);
        if (w == 0)
            __builtin_amdgcn_global_load_lds(
                (const __attribute__((address_space(1))) void*)
                    (src + 24576 + tid * 16),
                (__attribute__((address_space(3))) void*)(dst + 24576),
                16, 0, 0);
    };

    dmaW(0, 0);
    __syncthreads();                    // drains DMA: Wl[0] ready

    for (int it = 0; it < NC * NMT; ++it) {
        const int cur = it & 1;
        if (it + 1 < NC * NMT) dmaW(it + 1, cur ^ 1);   // async under MFMAs
        f32x4 acc[4][2];
        #pragma unroll
        for (int i = 0; i < 4; ++i)
            #pragma unroll
            for (int jj = 0; jj < 2; ++jj) acc[i][jj] = 0.f;
        #pragma unroll
        for (int t = 0; t < 6; ++t) {
            bf16x8 af[4];
            #pragma unroll
            for (int mi = 0; mi < 4; ++mi)
                af[mi] = *(const bf16x8*)
                    &Wl[cur][(16 * mi + li) * 200 + 32 * t + 8 * gi];
            #pragma unroll
            for (int mi = 0; mi < 4; ++mi)
                #pragma unroll
                for (int ni = 0; ni < 2; ++ni)
                    acc[mi][ni] = __builtin_amdgcn_mfma_f32_16x16x32_bf16(
                        xfrag[t][ni], af[mi], acc[mi][ni], 0, 0, 0);
        }
        const int c = it / NMT, j = it % NMT;
        if constexpr (sizeof(YT) == 2) {
            // full-line epilogue: assemble tile in LDS, store 256B rows
            bf16_t* et = (bf16_t*)Ustage;   // [64][136]
            #pragma unroll
            for (int mi = 0; mi < 4; ++mi)
                #pragma unroll
                for (int ni = 0; ni < 2; ++ni) {
                    bf16x4 v = { (bf16_t)acc[mi][ni][0], (bf16_t)acc[mi][ni][1],
                                 (bf16_t)acc[mi][ni][2], (bf16_t)acc[mi][ni][3] };
                    *(bf16x4*)&et[(16 * mi + li) * 136
                                  + 32 * w + 16 * ni + 4 * gi] = v;
                }
            __syncthreads();
            YT* Yb = Y + ga.yoff[z * NC + c] + (long)(64 * j) * N_PIX + n0;
            const int r0 = tid >> 4, p = tid & 15;
            #pragma unroll
            for (int j4 = 0; j4 < 4; ++j4) {
                const int row = r0 + 16 * j4;
                bf16x8 v = *(const bf16x8*)&et[row * 136 + 8 * p];
                *(bf16x8*)(Yb + (long)row * N_PIX + 8 * p) = v;
            }
        } else {
            // f32: direct stores already form 64B segments per m-row
            YT* Yb = Y + ga.yoff[z * NC + c] + (long)(64 * j) * N_PIX;
            #pragma unroll
            for (int mi = 0; mi < 4; ++mi)
                #pragma unroll
                for (int ni = 0; ni < 2; ++ni) {
                    YT* yp = Yb + (long)(16 * mi + li) * N_PIX
                               + n0 + 32 * w + 16 * ni + 4 * gi;
                    *(f32x4*)yp = acc[mi][ni];
                }
        }
        __syncthreads();   // Wl[cur] reads + et reads done; DMA(it+1) drained
    }
}

// ---------------- weight prep: f32 [576][192] -> padded bf16 tiles ----------
__global__ __launch_bounds__(256) void prep_w(const float* __restrict__ wq,
                                              bf16_t* __restrict__ wpad)
{
    const int j = blockIdx.x, tid = threadIdx.x;
    for (int idx = tid; idx < 64 * 192; idx += 256) {
        const int r = idx / 192, c = idx - r * 192;
        wpad[(long)j * WTILE + r * 200 + c] =
            (bf16_t)wq[(long)(64 * j + r) * KTOT + c];
    }
}

// ---------------- depthwise 3x3 + fused row L2-norm ----------------
__global__ __launch_bounds__(256) void dwconv3b(const bf16_t* __restrict__ Yin,
    const float* __restrict__ wdw, bf16_t* __restrict__ Z,
    float* __restrict__ invn)
{
    const int ch = blockIdx.x, sb = blockIdx.y;
    const int tid = threadIdx.x;
    const int x0 = (tid & 15) << 3;
    const int y0 = (tid >> 4) << 3;
    const bf16_t* __restrict__ inp = Yin + (long)(sb * C3 + ch) * N_PIX;
    bf16_t* __restrict__ outp = Z + (long)(sb * C3 + ch) * N_PIX;
    const float* wch = wdw + ch * 9;
    const float w00 = wch[0], w01 = wch[1], w02 = wch[2];
    const float w10 = wch[3], w11 = wch[4], w12 = wch[5];
    const float w20 = wch[6], w21 = wch[7], w22 = wch[8];
    const bool hasL = (x0 > 0), hasR = (x0 < 120);
    float A[10], B[10], Cr[10];
    auto loadrow = [&](int yy, float* r) {
        if (yy < 0 || yy > 127) {
            #pragma unroll
            for (int i = 0; i < 10; ++i) r[i] = 0.f;
            return;
        }
        const bf16_t* p = inp + (yy << 7);
        bf16x8 v = *(const bf16x8*)(p + x0);
        #pragma unroll
        for (int j = 0; j < 8; ++j) r[1 + j] = (float)v[j];
        r[0] = hasL ? (float)p[x0 - 1] : 0.f;
        r[9] = hasR ? (float)p[x0 + 8] : 0.f;
    };
    loadrow(y0 - 1, A);
    loadrow(y0,     B);
    float ss = 0.f;
    #pragma unroll
    for (int r = 0; r < 8; ++r) {
        loadrow(y0 + r + 1, Cr);
        bf16x8 ov;
        #pragma unroll
        for (int i = 0; i < 8; ++i) {
            float s;
            s = fmaf(w00, A[i],  fmaf(w01, A[i + 1],  w02 * A[i + 2]));
            s = fmaf(w10, B[i],  fmaf(w11, B[i + 1],  fmaf(w12, B[i + 2], s)));
            s = fmaf(w20, Cr[i], fmaf(w21, Cr[i + 1], fmaf(w22, Cr[i + 2], s)));
            ov[i] = (bf16_t)s;
            const float vb = (float)ov[i];
            ss = fmaf(vb, vb, ss);
        }
        *(bf16x8*)(outp + ((y0 + r) << 7) + x0) = ov;
        #pragma unroll
        for (int i = 0; i < 10; ++i) { A[i] = B[i]; B[i] = Cr[i]; }
    }
    if (ch < 384) {
        #pragma unroll
        for (int off = 32; off > 0; off >>= 1) ss += __shfl_down(ss, off);
        __shared__ float red[4];
        if ((tid & 63) == 0) red[tid >> 6] = ss;
        __syncthreads();
        if (tid == 0) {
            const float t = red[0] + red[1] + red[2] + red[3];
            const int row = (sb >> 2) * 1536 + (sb & 3) * 384 + ch;
            invn[row] = 1.f / fmaxf(sqrtf(t), 1e-12f);
        }
    }
}

// ---------------- MFMA score partials: all 4 combos share one LDS stage ------
__global__ __launch_bounds__(256) void scores_mfma(const bf16_t* __restrict__ Z,
                                                   float* __restrict__ part)
{
    const int c = blockIdx.x;
    const int bh = blockIdx.y;
    const int b = bh >> 2, h = bh & 3;
    __shared__ __align__(16) bf16_t T[4][48][72];   // qe, qd, ke, kd
    const int tid = threadIdx.x;
    const int m = tid >> 6;
    const int gi = (tid >> 4) & 3, li = tid & 15;
    const int qs = (m == 1 || m == 3) ? 1 : 0;
    const int ks = (m == 1 || m == 2) ? 1 : 0;
    f32x4 acc[3][3];
    #pragma unroll
    for (int i = 0; i < 3; ++i)
        #pragma unroll
        for (int j = 0; j < 3; ++j) acc[i][j] = 0.f;

    const int nbase = c * CHUNK;
    for (int k0 = 0; k0 < CHUNK; k0 += 64) {
        __syncthreads();
        for (int l = tid; l < 1536; l += 256) {
            const int t = l / 384;
            const int rem = l - t * 384;
            const int r = rem >> 3, s = rem & 7;
            const int sidx = (t < 2) ? t : (t - 2);
            const int qk = (t < 2) ? 0 : 1;
            const bf16_t* gp = Z + ((long)((sidx * 4 + b) * C3 + qk * 192 + h * 48 + r)) * N_PIX
                                 + nbase + k0 + s * 8;
            *(bf16x8*)&T[t][r][s * 8] = *(const bf16x8*)gp;
        }
        __syncthreads();
        #pragma unroll
        for (int k2 = 0; k2 < 64; k2 += 32) {
            bf16x8 af[3], bfr[3];
            #pragma unroll
            for (int i = 0; i < 3; ++i) {
                bf16x4 lo = *(const bf16x4*)&T[qs][16 * i + li][k2 + 4 * gi];
                bf16x4 hi = *(const bf16x4*)&T[qs][16 * i + li][k2 + 16 + 4 * gi];
                af[i] = __builtin_shufflevector(lo, hi, 0, 1, 2, 3, 4, 5, 6, 7);
            }
            #pragma unroll
            for (int j = 0; j < 3; ++j) {
                bf16x4 lo = *(const bf16x4*)&T[2 + ks][16 * j + li][k2 + 4 * gi];
                bf16x4 hi = *(const bf16x4*)&T[2 + ks][16 * j + li][k2 + 16 + 4 * gi];
                bfr[j] = __builtin_shufflevector(lo, hi, 0, 1, 2, 3, 4, 5, 6, 7);
            }
            #pragma unroll
            for (int i = 0; i < 3; ++i)
                #pragma unroll
                for (int j = 0; j < 3; ++j)
                    acc[i][j] = __builtin_amdgcn_mfma_f32_16x16x32_bf16(
                        af[i], bfr[j], acc[i][j], 0, 0, 0);
        }
    }
    const long base = ((long)(m * 16 + bh) * NCH + c) * 2304;
    #pragma unroll
    for (int i = 0; i < 3; ++i)
        #pragma unroll
        for (int j = 0; j < 3; ++j) {
            const int e = 16 * j + li;
            #pragma unroll
            for (int r = 0; r < 4; ++r) {
                const int d = 16 * i + 4 * gi + r;
                part[base + d * 48 + e] = acc[i][j][r];
            }
        }
}

// ---------------- reduce partials, scale by norms+temperature, softmax -------
__global__ __launch_bounds__(256) void reduce_softmax(const float* __restrict__ part,
    const float* __restrict__ invn, const float* __restrict__ temp,
    float* __restrict__ attn)
{
    const int mbh = blockIdx.x;                 // 64
    const int m = mbh >> 4, b = (mbh >> 2) & 3, h = mbh & 3;
    const int qs = (m == 1 || m == 3) ? 1 : 0;
    const int ks = (m == 1 || m == 2) ? 1 : 0;
    __shared__ float sm[48][48];
    const int tid = threadIdx.x;
    const long pbase = (long)mbh * NCH * 2304;
    const float T = temp[h];
    for (int idx = tid; idx < 2304; idx += 256) {
        float v = 0.f;
        #pragma unroll 8
        for (int c = 0; c < NCH; ++c) v += part[pbase + c * 2304 + idx];
        const int d = idx / 48, e = idx % 48;
        const float iq = invn[(qs * 4 + b) * 384 + h * 48 + d];
        const float ik = invn[(ks * 4 + b) * 384 + 192 + h * 48 + e];
        sm[d][e] = v * iq * ik * T;
    }
    __syncthreads();
    if (tid < 48) {
        float mx = -1e30f;
        #pragma unroll
        for (int e = 0; e < 48; ++e) mx = fmaxf(mx, sm[tid][e]);
        float sum = 0.f;
        #pragma unroll
        for (int e = 0; e < 48; ++e) {
            const float v = __expf(sm[tid][e] - mx);
            sm[tid][e] = v;
            sum += v;
        }
        const float inv = 1.f / sum;
        const long abase = (long)mbh * 2304 + (long)tid * 48;
        #pragma unroll
        for (int e = 0; e < 48; ++e) attn[abase + e] = sm[tid][e] * inv;
    }
}

// -------- fold attn into projection; emit padded bf16 W tiles directly ------
// m==3 (inter_de): einsum '...de,bhen->bhdn' SUMS the ellipsis dims.
__global__ __launch_bounds__(256) void make_M(const float* __restrict__ attn,
                                              WPtrs wp, bf16_t* __restrict__ Mpad)
{
    const int h = blockIdx.x & 3;
    const int b = (blockIdx.x >> 2) & 3;
    const int m = blockIdx.x >> 4;              // grid 64
    __shared__ float A[48][48];
    const int tid = threadIdx.x;
    if (m == 3) {
        for (int l = tid; l < 2304; l += 256) {
            float s = 0.f;
            #pragma unroll
            for (int bb = 0; bb < 16; ++bb)
                s += attn[(long)(48 + bb) * 2304 + l];
            A[l / 48][l % 48] = s;
        }
    } else {
        const long ab = (long)(m * 16 + b * 4 + h) * 2304;
        for (int l = tid; l < 2304; l += 256)
            A[l / 48][l % 48] = attn[ab + l];
    }
    __syncthreads();
    const float* W = wp.p[m];
    bf16_t* Mo = Mpad + (long)(m * 4 + b) * 3 * WTILE;
    for (int o = tid >> 4; o < 192; o += 16) {
        const float* wrow = W + (long)o * 192 + h * 48;
        bf16_t* orow = Mo + (long)(o >> 6) * WTILE + (o & 63) * 200 + h * 48;
        for (int e2 = tid & 15; e2 < 48; e2 += 16) {
            float s = 0.f;
            #pragma unroll
            for (int d = 0; d < 48; ++d) s = fmaf(wrow[d], A[d][e2], s);
            orow[e2] = (bf16_t)s;
        }
    }
}

extern "C" void kernel_launch(void* const* d_in, const int* in_sizes, int n_in,
                              void* d_out, int out_size, void* d_ws, size_t ws_size,
                              hipStream_t stream)
{
    const float* e     = (const float*)d_in[0];
    const float* d     = (const float*)d_in[1];
    const float* temp  = (const float*)d_in[2];
    const float* w_qkv = (const float*)d_in[3];
    const float* w_dw  = (const float*)d_in[4];
    const float* w_p1  = (const float*)d_in[5];
    const float* w_p2  = (const float*)d_in[6];
    const float* w_p3  = (const float*)d_in[7];
    const float* w_p4  = (const float*)d_in[8];
    float* out = (float*)d_out;
    float* ws  = (float*)d_ws;

    // workspace layout (float units)
    bf16_t* zraw = (bf16_t*)ws;                // 75,497,472 bf16 (qkv raw)
    bf16_t* zb   = (bf16_t*)(ws + 37748736L);  // 75,497,472 bf16
    float* attn  = ws + 75497472L;             // 147,456
    float* invn  = ws + 75644928L;             // 3,072
    bf16_t* Wqpad = (bf16_t*)(ws + 75648000L); // 9*12800 bf16
    bf16_t* Mpad  = (bf16_t*)(ws + 75710000L); // 16*3*12800 bf16
    float* part  = ws;                         // reuses dead zraw region

    const long sXin = (long)CC * N_PIX;
    const long sQKV = (long)C3 * N_PIX;

    // 0) pre-convert qkv weights to padded bf16 tiles
    prep_w<<<dim3(9), 256, 0, stream>>>(w_qkv, Wqpad);
    // 1) pointwise qkv GEMM, bf16 out — z = (s,b) panel; 9 m-tiles per block
    GArgs gq{};
    for (int z = 0; z < 8; ++z) {
        gq.xoff[z] = (long)(z & 3) * sXin;
        gq.yoff[z] = (long)z * sQKV;
        gq.woff[z] = 0;
        gq.sel[z] = z >> 2;
    }
    gemm_mloop<float, bf16_t, 1, 9><<<dim3(128, 8), 256, 0, stream>>>(
        gq, e, d, zraw, Wqpad);
    // 2) depthwise 3x3 (bf16 -> bf16) + fused q/k row norms
    dwconv3b<<<dim3(C3, 8), 256, 0, stream>>>(zraw, w_dw, zb, invn);
    // 3) MFMA score partials, 4 combos fused
    scores_mfma<<<dim3(NCH, 16), 256, 0, stream>>>(zb, part);
    // 4) reduce + scale + softmax
    reduce_softmax<<<dim3(64), 256, 0, stream>>>(part, invn, temp, attn);
    // 5) fold attn into projection matrices (padded bf16 tiles)
    WPtrs wpj; wpj.p[0] = w_p1; wpj.p[1] = w_p2; wpj.p[2] = w_p3; wpj.p[3] = w_p4;
    make_M<<<dim3(64), 256, 0, stream>>>(attn, wpj, Mpad);
    // 6) fused (proj ∘ attn) @ V: z = V panel (s,b); 2 combos x 3 m-tiles per
    //    block, V read ONCE. s=0 panels serve m in {0,3}; s=1 serve {1,2}.
    GArgs gm{};
    for (int z = 0; z < 8; ++z) {
        const int s = z >> 2, b = z & 3;
        gm.xoff[z] = ((long)((s * 4 + b) * C3 + 384)) * N_PIX;
        gm.sel[z] = 0;
        for (int c = 0; c < 2; ++c) {
            const int midx = (s == 0) ? (c ? 3 : 0) : (c ? 2 : 1);
            gm.woff[2 * z + c] = (long)(midx * 4 + b) * 3 * WTILE;
            gm.yoff[2 * z + c] = (long)(midx * 4 + b) * sXin;
        }
    }
    gemm_mloop<bf16_t, float, 2, 3><<<dim3(128, 8), 256, 0, stream>>>(
        gm, zb, zb, out, Mpad);
}